// Round 1
// baseline (351.609 us; speedup 1.0000x reference)
//
#include <hip/hip_runtime.h>

#define H_DIM 1024
#define I_DIM 512
#define NE 8
#define SI_DIM 1024
#define NT 2048

typedef __bf16 bf16;
typedef __bf16 bf16x4 __attribute__((ext_vector_type(4)));
typedef __bf16 bf16x8 __attribute__((ext_vector_type(8)));
typedef float f32x4 __attribute__((ext_vector_type(4)));

#define LDK 72  // padded LDS leading dim (bf16 elems); 144B = 9*16B keeps b128 alignment

// ---- workspace layout (bytes) ----
#define WS_CNT 0                                   // int[8]
#define WS_WSUM 32                                 // float[8]
#define WS_LISTS 256                               // int[8][2048]
#define WS_ACT_E (128 * 1024)                      // bf16[8][2048][512]
#define ACT_E_BYTES (NE * NT * I_DIM * 2)
#define WS_ACT_S (WS_ACT_E + ACT_E_BYTES)          // bf16[2048][1024]

__device__ __forceinline__ bf16x4 cvt4(f32x4 v) {
  bf16x4 r;
  r.x = (bf16)v.x; r.y = (bf16)v.y; r.z = (bf16)v.z; r.w = (bf16)v.w;
  return r;
}

// ---------------- router: one wave per token ----------------
__global__ __launch_bounds__(256) void router_kernel(
    const float* __restrict__ x, const float* __restrict__ gw,
    const float* __restrict__ lb, int* __restrict__ cnt,
    float* __restrict__ wsum, int* __restrict__ lists) {
  const int lane = threadIdx.x & 63;
  const int t = blockIdx.x * 4 + (threadIdx.x >> 6);
  const float* xr = x + (size_t)t * H_DIM;

  float s[NE];
#pragma unroll
  for (int e = 0; e < NE; e++) s[e] = 0.f;
  for (int k = lane; k < H_DIM; k += 64) {
    float xv = xr[k];
#pragma unroll
    for (int e = 0; e < NE; e++) s[e] += xv * gw[e * H_DIM + k];
  }
#pragma unroll
  for (int e = 0; e < NE; e++) {
    float v = s[e];
#pragma unroll
    for (int off = 32; off > 0; off >>= 1) v += __shfl_xor(v, off);
    s[e] = v;
  }
  if (lane == 0) {
    float sc[NE];
#pragma unroll
    for (int e = 0; e < NE; e++) sc[e] = 1.f / (1.f + expf(-(s[e] + lb[e])));
    int i1 = 0;
#pragma unroll
    for (int e = 1; e < NE; e++)
      if (sc[e] > sc[i1]) i1 = e;      // strict > : ties -> lowest index (lax.top_k)
    int i2 = -1;
#pragma unroll
    for (int e = 0; e < NE; e++) {
      if (e == i1) continue;
      if (i2 < 0 || sc[e] > sc[i2]) i2 = e;
    }
    float w1 = sc[i1], w2 = sc[i2];
    float inv = 1.f / (w1 + w2 + 1e-8f);
    w1 *= inv; w2 *= inv;
    int p1 = atomicAdd(&cnt[i1], 1);
    lists[i1 * NT + p1] = t;
    atomicAdd(&wsum[i1], w1);
    int p2 = atomicAdd(&cnt[i2], 1);
    lists[i2 * NT + p2] = t;
    atomicAdd(&wsum[i2], w2);
  }
}

// ---------------- fused gate+up GEMM -> silu(g)*u, bf16 act ----------------
// grid: (16 colTiles, 32 rowTiles, 9 [8 experts + shared])
__global__ __launch_bounds__(256, 2) void gateup_kernel(
    const float* __restrict__ x, const float* __restrict__ eg,
    const float* __restrict__ eu, const float* __restrict__ sg,
    const float* __restrict__ su, const int* __restrict__ cnt,
    const int* __restrict__ lists, bf16* __restrict__ act_e,
    bf16* __restrict__ act_s) {
  const int z = blockIdx.z;
  const int colTile = blockIdx.x;
  const int rowTile = blockIdx.y;

  int cnt_e, ldAct;
  const float *Wg, *Wu;
  const int* list = nullptr;
  bf16* act;
  if (z < NE) {
    if (colTile >= I_DIM / 64) return;
    cnt_e = cnt[z];
    if (rowTile * 64 >= cnt_e) return;
    Wg = eg + (size_t)z * I_DIM * H_DIM;
    Wu = eu + (size_t)z * I_DIM * H_DIM;
    act = act_e + (size_t)z * NT * I_DIM;
    ldAct = I_DIM;
    list = lists + z * NT;
  } else {
    cnt_e = NT;
    Wg = sg; Wu = su;
    act = act_s;
    ldAct = SI_DIM;
  }

  __shared__ int rows_s[64];
  __shared__ __align__(16) bf16 As[64][LDK];
  __shared__ __align__(16) bf16 Bg[64][LDK];
  __shared__ __align__(16) bf16 Bu[64][LDK];

  const int tid = threadIdx.x;
  if (tid < 64) {
    int r = rowTile * 64 + tid;
    rows_s[tid] = (z < NE) ? ((r < cnt_e) ? list[r] : -1) : r;
  }
  __syncthreads();

  const int lane = tid & 63;
  const int wave = tid >> 6;
  const int mw = (wave >> 1) * 32;
  const int nw = (wave & 1) * 32;
  const int l15 = lane & 15;
  const int quad = lane >> 4;
  const int nBase = colTile * 64;

  f32x4 accg[2][2] = {};
  f32x4 accu[2][2] = {};

  for (int k0 = 0; k0 < H_DIM; k0 += 64) {
#pragma unroll
    for (int it = 0; it < 4; it++) {
      int i = tid + it * 256;  // 0..1023 : 64 rows x 16 float4
      int r = i >> 4;
      int c = (i & 15) * 4;
      int tok = rows_s[r];
      f32x4 av = {0.f, 0.f, 0.f, 0.f};
      if (tok >= 0) av = *(const f32x4*)(x + (size_t)tok * H_DIM + k0 + c);
      *(bf16x4*)&As[r][c] = cvt4(av);
      f32x4 gv = *(const f32x4*)(Wg + (size_t)(nBase + r) * H_DIM + k0 + c);
      *(bf16x4*)&Bg[r][c] = cvt4(gv);
      f32x4 uv = *(const f32x4*)(Wu + (size_t)(nBase + r) * H_DIM + k0 + c);
      *(bf16x4*)&Bu[r][c] = cvt4(uv);
    }
    __syncthreads();
#pragma unroll
    for (int kk = 0; kk < 2; kk++) {
      int kof = kk * 32 + quad * 8;
      bf16x8 a0 = *(const bf16x8*)&As[mw + l15][kof];
      bf16x8 a1 = *(const bf16x8*)&As[mw + 16 + l15][kof];
      bf16x8 g0 = *(const bf16x8*)&Bg[nw + l15][kof];
      bf16x8 g1 = *(const bf16x8*)&Bg[nw + 16 + l15][kof];
      bf16x8 u0 = *(const bf16x8*)&Bu[nw + l15][kof];
      bf16x8 u1 = *(const bf16x8*)&Bu[nw + 16 + l15][kof];
      accg[0][0] = __builtin_amdgcn_mfma_f32_16x16x32_bf16(a0, g0, accg[0][0], 0, 0, 0);
      accg[0][1] = __builtin_amdgcn_mfma_f32_16x16x32_bf16(a0, g1, accg[0][1], 0, 0, 0);
      accg[1][0] = __builtin_amdgcn_mfma_f32_16x16x32_bf16(a1, g0, accg[1][0], 0, 0, 0);
      accg[1][1] = __builtin_amdgcn_mfma_f32_16x16x32_bf16(a1, g1, accg[1][1], 0, 0, 0);
      accu[0][0] = __builtin_amdgcn_mfma_f32_16x16x32_bf16(a0, u0, accu[0][0], 0, 0, 0);
      accu[0][1] = __builtin_amdgcn_mfma_f32_16x16x32_bf16(a0, u1, accu[0][1], 0, 0, 0);
      accu[1][0] = __builtin_amdgcn_mfma_f32_16x16x32_bf16(a1, u0, accu[1][0], 0, 0, 0);
      accu[1][1] = __builtin_amdgcn_mfma_f32_16x16x32_bf16(a1, u1, accu[1][1], 0, 0, 0);
    }
    __syncthreads();
  }

#pragma unroll
  for (int am = 0; am < 2; am++) {
#pragma unroll
    for (int bn = 0; bn < 2; bn++) {
      int c = nBase + nw + bn * 16 + l15;
#pragma unroll
      for (int rg = 0; rg < 4; rg++) {
        int r = rowTile * 64 + mw + am * 16 + quad * 4 + rg;
        if (r < cnt_e) {
          float g = accg[am][bn][rg];
          float u = accu[am][bn][rg];
          float a = (g / (1.f + __expf(-g))) * u;
          act[(size_t)r * ldAct + c] = (bf16)a;
        }
      }
    }
  }
}

// ---------------- down GEMM: y = act @ Wd^T, atomicAdd wmean*y into out ----------------
// grid: (16 colTiles over H, 32 rowTiles, 9)
__global__ __launch_bounds__(256, 2) void down_kernel(
    const bf16* __restrict__ act_e, const bf16* __restrict__ act_s,
    const float* __restrict__ ed, const float* __restrict__ sd,
    const int* __restrict__ cnt, const float* __restrict__ wsum,
    const int* __restrict__ lists, float* __restrict__ out) {
  const int z = blockIdx.z;
  const int colTile = blockIdx.x;
  const int rowTile = blockIdx.y;

  int cnt_e, K;
  const bf16* act;
  const float* Wd;
  const int* list = nullptr;
  float wm;
  if (z < NE) {
    cnt_e = cnt[z];
    if (rowTile * 64 >= cnt_e) return;
    act = act_e + (size_t)z * NT * I_DIM;
    K = I_DIM;
    Wd = ed + (size_t)z * H_DIM * I_DIM;
    wm = wsum[z] / (float)(cnt_e > 0 ? cnt_e : 1);
    list = lists + z * NT;
  } else {
    cnt_e = NT;
    act = act_s;
    K = SI_DIM;
    Wd = sd;
    wm = 1.f;
  }

  __shared__ int rows_s[64];
  __shared__ __align__(16) bf16 As[64][LDK];
  __shared__ __align__(16) bf16 Bs[64][LDK];

  const int tid = threadIdx.x;
  if (tid < 64) {
    int r = rowTile * 64 + tid;
    rows_s[tid] = (z < NE) ? ((r < cnt_e) ? list[r] : -1) : r;
  }
  __syncthreads();

  const int lane = tid & 63;
  const int wave = tid >> 6;
  const int mw = (wave >> 1) * 32;
  const int nw = (wave & 1) * 32;
  const int l15 = lane & 15;
  const int quad = lane >> 4;
  const int nBase = colTile * 64;

  f32x4 acc[2][2] = {};

  for (int k0 = 0; k0 < K; k0 += 64) {
#pragma unroll
    for (int it = 0; it < 2; it++) {
      int i = tid + it * 256;  // 0..511 : 64 rows x 8 chunks of 8 bf16
      int r = i >> 3;
      int c = (i & 7) * 8;
      *(bf16x8*)&As[r][c] =
          *(const bf16x8*)(act + (size_t)(rowTile * 64 + r) * K + k0 + c);
    }
#pragma unroll
    for (int it = 0; it < 4; it++) {
      int i = tid + it * 256;
      int r = i >> 4;
      int c = (i & 15) * 4;
      f32x4 wv = *(const f32x4*)(Wd + (size_t)(nBase + r) * K + k0 + c);
      *(bf16x4*)&Bs[r][c] = cvt4(wv);
    }
    __syncthreads();
#pragma unroll
    for (int kk = 0; kk < 2; kk++) {
      int kof = kk * 32 + quad * 8;
      bf16x8 a0 = *(const bf16x8*)&As[mw + l15][kof];
      bf16x8 a1 = *(const bf16x8*)&As[mw + 16 + l15][kof];
      bf16x8 b0 = *(const bf16x8*)&Bs[nw + l15][kof];
      bf16x8 b1 = *(const bf16x8*)&Bs[nw + 16 + l15][kof];
      acc[0][0] = __builtin_amdgcn_mfma_f32_16x16x32_bf16(a0, b0, acc[0][0], 0, 0, 0);
      acc[0][1] = __builtin_amdgcn_mfma_f32_16x16x32_bf16(a0, b1, acc[0][1], 0, 0, 0);
      acc[1][0] = __builtin_amdgcn_mfma_f32_16x16x32_bf16(a1, b0, acc[1][0], 0, 0, 0);
      acc[1][1] = __builtin_amdgcn_mfma_f32_16x16x32_bf16(a1, b1, acc[1][1], 0, 0, 0);
    }
    __syncthreads();
  }

#pragma unroll
  for (int am = 0; am < 2; am++) {
#pragma unroll
    for (int bn = 0; bn < 2; bn++) {
      int c = nBase + nw + bn * 16 + l15;
#pragma unroll
      for (int rg = 0; rg < 4; rg++) {
        int rl = mw + am * 16 + quad * 4 + rg;
        int tok = rows_s[rl];
        if (tok >= 0) {
          atomicAdd(&out[(size_t)tok * H_DIM + c], wm * acc[am][bn][rg]);
        }
      }
    }
  }
}

extern "C" void kernel_launch(void* const* d_in, const int* in_sizes, int n_in,
                              void* d_out, int out_size, void* d_ws,
                              size_t ws_size, hipStream_t stream) {
  (void)in_sizes; (void)n_in; (void)out_size; (void)ws_size;
  const float* x  = (const float*)d_in[0];
  const float* gw = (const float*)d_in[1];
  const float* lb = (const float*)d_in[2];
  const float* eg = (const float*)d_in[3];
  const float* eu = (const float*)d_in[4];
  const float* ed = (const float*)d_in[5];
  const float* sg = (const float*)d_in[6];
  const float* su = (const float*)d_in[7];
  const float* sd = (const float*)d_in[8];
  float* out = (float*)d_out;
  char* ws = (char*)d_ws;

  int* cnt     = (int*)(ws + WS_CNT);
  float* wsum  = (float*)(ws + WS_WSUM);
  int* lists   = (int*)(ws + WS_LISTS);
  bf16* act_e  = (bf16*)(ws + WS_ACT_E);
  bf16* act_s  = (bf16*)(ws + WS_ACT_S);

  hipMemsetAsync(ws, 0, 64, stream);                                  // cnt + wsum
  hipMemsetAsync(d_out, 0, (size_t)NT * H_DIM * sizeof(float), stream);

  router_kernel<<<NT / 4, 256, 0, stream>>>(x, gw, lb, cnt, wsum, lists);
  gateup_kernel<<<dim3(16, 32, 9), 256, 0, stream>>>(x, eg, eu, sg, su, cnt,
                                                     lists, act_e, act_s);
  down_kernel<<<dim3(16, 32, 9), 256, 0, stream>>>(act_e, act_s, ed, sd, cnt,
                                                   wsum, lists, out);
}

// Round 2
// 267.395 us; speedup vs baseline: 1.3149x; 1.3149x over previous
//
#include <hip/hip_runtime.h>

#define H_DIM 1024
#define I_DIM 512
#define NE 8
#define SI_DIM 1024
#define NT 2048

typedef __bf16 bf16;
typedef __bf16 bf16x4 __attribute__((ext_vector_type(4)));
typedef __bf16 bf16x8 __attribute__((ext_vector_type(8)));
typedef float f32x4 __attribute__((ext_vector_type(4)));

#define LDK 72  // padded LDS leading dim (bf16 elems); 144B = 9*16B keeps b128 alignment

// ---- workspace layout (bytes) ----
#define WS_CNT 0                                   // int[8]
#define WS_WSUM 32                                 // float[8]
#define WS_LISTS 256                               // int[8][2048]
#define WS_TOPI (256 + 65536)                      // int2[2048]
#define WS_TOPW (WS_TOPI + 16384)                  // float2[2048]
#define WS_ACT_E (128 * 1024)                      // bf16[8][2048][512]
#define ACT_E_BYTES (NE * NT * I_DIM * 2)
#define WS_ACT_S (WS_ACT_E + ACT_E_BYTES)          // bf16[2048][1024]

__device__ __forceinline__ bf16x4 cvt4(f32x4 v) {
  bf16x4 r;
  r.x = (bf16)v.x; r.y = (bf16)v.y; r.z = (bf16)v.z; r.w = (bf16)v.w;
  return r;
}

// ---------------- router: one wave per token, NO atomics ----------------
__global__ __launch_bounds__(256) void router_kernel(
    const float* __restrict__ x, const float* __restrict__ gw,
    const float* __restrict__ lb, int2* __restrict__ topi,
    float2* __restrict__ topw) {
  const int lane = threadIdx.x & 63;
  const int t = blockIdx.x * 4 + (threadIdx.x >> 6);
  const float* xr = x + (size_t)t * H_DIM;

  float s[NE];
#pragma unroll
  for (int e = 0; e < NE; e++) s[e] = 0.f;
#pragma unroll
  for (int k0 = 0; k0 < H_DIM; k0 += 256) {
    f32x4 xv = *(const f32x4*)(xr + k0 + lane * 4);
#pragma unroll
    for (int e = 0; e < NE; e++) {
      f32x4 gv = *(const f32x4*)(gw + e * H_DIM + k0 + lane * 4);
      s[e] += xv.x * gv.x + xv.y * gv.y + xv.z * gv.z + xv.w * gv.w;
    }
  }
#pragma unroll
  for (int e = 0; e < NE; e++) {
    float v = s[e];
#pragma unroll
    for (int off = 32; off > 0; off >>= 1) v += __shfl_xor(v, off);
    s[e] = v;
  }
  if (lane == 0) {
    float sc[NE];
#pragma unroll
    for (int e = 0; e < NE; e++) sc[e] = 1.f / (1.f + expf(-(s[e] + lb[e])));
    int i1 = 0;
#pragma unroll
    for (int e = 1; e < NE; e++)
      if (sc[e] > sc[i1]) i1 = e;      // strict > : ties -> lowest index (lax.top_k)
    int i2 = -1;
#pragma unroll
    for (int e = 0; e < NE; e++) {
      if (e == i1) continue;
      if (i2 < 0 || sc[e] > sc[i2]) i2 = e;
    }
    float w1 = sc[i1], w2 = sc[i2];
    float inv = 1.f / (w1 + w2 + 1e-8f);
    topi[t] = make_int2(i1, i2);
    topw[t] = make_float2(w1 * inv, w2 * inv);
  }
}

// ---------------- build: 1 block, 8 waves, one wave per expert, NO atomics ----------------
__global__ __launch_bounds__(512) void build_kernel(
    const int2* __restrict__ topi, const float2* __restrict__ topw,
    int* __restrict__ cnt, float* __restrict__ wsum, int* __restrict__ lists) {
  const int e = threadIdx.x >> 6;   // wave id == expert id
  const int lane = threadIdx.x & 63;
  int c = 0;
  float wacc = 0.f;
  for (int t0 = 0; t0 < NT; t0 += 64) {
    int t = t0 + lane;
    int2 ti = topi[t];
    float2 tw = topw[t];
    bool hit = (ti.x == e) || (ti.y == e);
    float w = (ti.x == e) ? tw.x : ((ti.y == e) ? tw.y : 0.f);
    unsigned long long m = __ballot(hit);
    int pre = __popcll(m & ((1ull << lane) - 1ull));
    if (hit) lists[e * NT + c + pre] = t;
    c += __popcll(m);
#pragma unroll
    for (int off = 32; off > 0; off >>= 1) w += __shfl_xor(w, off);
    wacc += w;
  }
  if (lane == 0) {
    cnt[e] = c;
    wsum[e] = wacc;
  }
}

// ---------------- fused gate+up GEMM -> silu(g)*u, bf16 act ----------------
// grid: (16 colTiles, 32 rowTiles, 9 [8 experts + shared])
__global__ __launch_bounds__(256, 2) void gateup_kernel(
    const float* __restrict__ x, const float* __restrict__ eg,
    const float* __restrict__ eu, const float* __restrict__ sg,
    const float* __restrict__ su, const int* __restrict__ cnt,
    const int* __restrict__ lists, bf16* __restrict__ act_e,
    bf16* __restrict__ act_s) {
  const int z = blockIdx.z;
  const int colTile = blockIdx.x;
  const int rowTile = blockIdx.y;

  int cnt_e, ldAct;
  const float *Wg, *Wu;
  const int* list = nullptr;
  bf16* act;
  if (z < NE) {
    if (colTile >= I_DIM / 64) return;
    cnt_e = cnt[z];
    if (rowTile * 64 >= cnt_e) return;
    Wg = eg + (size_t)z * I_DIM * H_DIM;
    Wu = eu + (size_t)z * I_DIM * H_DIM;
    act = act_e + (size_t)z * NT * I_DIM;
    ldAct = I_DIM;
    list = lists + z * NT;
  } else {
    cnt_e = NT;
    Wg = sg; Wu = su;
    act = act_s;
    ldAct = SI_DIM;
  }

  __shared__ int rows_s[64];
  __shared__ __align__(16) bf16 As[64][LDK];
  __shared__ __align__(16) bf16 Bg[64][LDK];
  __shared__ __align__(16) bf16 Bu[64][LDK];

  const int tid = threadIdx.x;
  if (tid < 64) {
    int r = rowTile * 64 + tid;
    rows_s[tid] = (z < NE) ? ((r < cnt_e) ? list[r] : -1) : r;
  }
  __syncthreads();

  const int lane = tid & 63;
  const int wave = tid >> 6;
  const int mw = (wave >> 1) * 32;
  const int nw = (wave & 1) * 32;
  const int l15 = lane & 15;
  const int quad = lane >> 4;
  const int nBase = colTile * 64;

  f32x4 accg[2][2] = {};
  f32x4 accu[2][2] = {};

  for (int k0 = 0; k0 < H_DIM; k0 += 64) {
#pragma unroll
    for (int it = 0; it < 4; it++) {
      int i = tid + it * 256;  // 0..1023 : 64 rows x 16 float4
      int r = i >> 4;
      int c = (i & 15) * 4;
      int tok = rows_s[r];
      f32x4 av = {0.f, 0.f, 0.f, 0.f};
      if (tok >= 0) av = *(const f32x4*)(x + (size_t)tok * H_DIM + k0 + c);
      *(bf16x4*)&As[r][c] = cvt4(av);
      f32x4 gv = *(const f32x4*)(Wg + (size_t)(nBase + r) * H_DIM + k0 + c);
      *(bf16x4*)&Bg[r][c] = cvt4(gv);
      f32x4 uv = *(const f32x4*)(Wu + (size_t)(nBase + r) * H_DIM + k0 + c);
      *(bf16x4*)&Bu[r][c] = cvt4(uv);
    }
    __syncthreads();
#pragma unroll
    for (int kk = 0; kk < 2; kk++) {
      int kof = kk * 32 + quad * 8;
      bf16x8 a0 = *(const bf16x8*)&As[mw + l15][kof];
      bf16x8 a1 = *(const bf16x8*)&As[mw + 16 + l15][kof];
      bf16x8 g0 = *(const bf16x8*)&Bg[nw + l15][kof];
      bf16x8 g1 = *(const bf16x8*)&Bg[nw + 16 + l15][kof];
      bf16x8 u0 = *(const bf16x8*)&Bu[nw + l15][kof];
      bf16x8 u1 = *(const bf16x8*)&Bu[nw + 16 + l15][kof];
      accg[0][0] = __builtin_amdgcn_mfma_f32_16x16x32_bf16(a0, g0, accg[0][0], 0, 0, 0);
      accg[0][1] = __builtin_amdgcn_mfma_f32_16x16x32_bf16(a0, g1, accg[0][1], 0, 0, 0);
      accg[1][0] = __builtin_amdgcn_mfma_f32_16x16x32_bf16(a1, g0, accg[1][0], 0, 0, 0);
      accg[1][1] = __builtin_amdgcn_mfma_f32_16x16x32_bf16(a1, g1, accg[1][1], 0, 0, 0);
      accu[0][0] = __builtin_amdgcn_mfma_f32_16x16x32_bf16(a0, u0, accu[0][0], 0, 0, 0);
      accu[0][1] = __builtin_amdgcn_mfma_f32_16x16x32_bf16(a0, u1, accu[0][1], 0, 0, 0);
      accu[1][0] = __builtin_amdgcn_mfma_f32_16x16x32_bf16(a1, u0, accu[1][0], 0, 0, 0);
      accu[1][1] = __builtin_amdgcn_mfma_f32_16x16x32_bf16(a1, u1, accu[1][1], 0, 0, 0);
    }
    __syncthreads();
  }

#pragma unroll
  for (int am = 0; am < 2; am++) {
#pragma unroll
    for (int bn = 0; bn < 2; bn++) {
      int c = nBase + nw + bn * 16 + l15;
#pragma unroll
      for (int rg = 0; rg < 4; rg++) {
        int r = rowTile * 64 + mw + am * 16 + quad * 4 + rg;
        if (r < cnt_e) {
          float g = accg[am][bn][rg];
          float u = accu[am][bn][rg];
          float a = (g / (1.f + __expf(-g))) * u;
          act[(size_t)r * ldAct + c] = (bf16)a;
        }
      }
    }
  }
}

// ---------------- down GEMM: y = act @ Wd^T, atomicAdd wmean*y into out ----------------
// grid: (16 colTiles over H, 32 rowTiles, 9)
__global__ __launch_bounds__(256, 2) void down_kernel(
    const bf16* __restrict__ act_e, const bf16* __restrict__ act_s,
    const float* __restrict__ ed, const float* __restrict__ sd,
    const int* __restrict__ cnt, const float* __restrict__ wsum,
    const int* __restrict__ lists, float* __restrict__ out) {
  const int z = blockIdx.z;
  const int colTile = blockIdx.x;
  const int rowTile = blockIdx.y;

  int cnt_e, K;
  const bf16* act;
  const float* Wd;
  const int* list = nullptr;
  float wm;
  if (z < NE) {
    cnt_e = cnt[z];
    if (rowTile * 64 >= cnt_e) return;
    act = act_e + (size_t)z * NT * I_DIM;
    K = I_DIM;
    Wd = ed + (size_t)z * H_DIM * I_DIM;
    wm = wsum[z] / (float)(cnt_e > 0 ? cnt_e : 1);
    list = lists + z * NT;
  } else {
    cnt_e = NT;
    act = act_s;
    K = SI_DIM;
    Wd = sd;
    wm = 1.f;
  }

  __shared__ int rows_s[64];
  __shared__ __align__(16) bf16 As[64][LDK];
  __shared__ __align__(16) bf16 Bs[64][LDK];

  const int tid = threadIdx.x;
  if (tid < 64) {
    int r = rowTile * 64 + tid;
    rows_s[tid] = (z < NE) ? ((r < cnt_e) ? list[r] : -1) : r;
  }
  __syncthreads();

  const int lane = tid & 63;
  const int wave = tid >> 6;
  const int mw = (wave >> 1) * 32;
  const int nw = (wave & 1) * 32;
  const int l15 = lane & 15;
  const int quad = lane >> 4;
  const int nBase = colTile * 64;

  f32x4 acc[2][2] = {};

  for (int k0 = 0; k0 < K; k0 += 64) {
#pragma unroll
    for (int it = 0; it < 2; it++) {
      int i = tid + it * 256;  // 0..511 : 64 rows x 8 chunks of 8 bf16
      int r = i >> 3;
      int c = (i & 7) * 8;
      *(bf16x8*)&As[r][c] =
          *(const bf16x8*)(act + (size_t)(rowTile * 64 + r) * K + k0 + c);
    }
#pragma unroll
    for (int it = 0; it < 4; it++) {
      int i = tid + it * 256;
      int r = i >> 4;
      int c = (i & 15) * 4;
      f32x4 wv = *(const f32x4*)(Wd + (size_t)(nBase + r) * K + k0 + c);
      *(bf16x4*)&Bs[r][c] = cvt4(wv);
    }
    __syncthreads();
#pragma unroll
    for (int kk = 0; kk < 2; kk++) {
      int kof = kk * 32 + quad * 8;
      bf16x8 a0 = *(const bf16x8*)&As[mw + l15][kof];
      bf16x8 a1 = *(const bf16x8*)&As[mw + 16 + l15][kof];
      bf16x8 b0 = *(const bf16x8*)&Bs[nw + l15][kof];
      bf16x8 b1 = *(const bf16x8*)&Bs[nw + 16 + l15][kof];
      acc[0][0] = __builtin_amdgcn_mfma_f32_16x16x32_bf16(a0, b0, acc[0][0], 0, 0, 0);
      acc[0][1] = __builtin_amdgcn_mfma_f32_16x16x32_bf16(a0, b1, acc[0][1], 0, 0, 0);
      acc[1][0] = __builtin_amdgcn_mfma_f32_16x16x32_bf16(a1, b0, acc[1][0], 0, 0, 0);
      acc[1][1] = __builtin_amdgcn_mfma_f32_16x16x32_bf16(a1, b1, acc[1][1], 0, 0, 0);
    }
    __syncthreads();
  }

#pragma unroll
  for (int am = 0; am < 2; am++) {
#pragma unroll
    for (int bn = 0; bn < 2; bn++) {
      int c = nBase + nw + bn * 16 + l15;
#pragma unroll
      for (int rg = 0; rg < 4; rg++) {
        int rl = mw + am * 16 + quad * 4 + rg;
        int tok = rows_s[rl];
        if (tok >= 0) {
          atomicAdd(&out[(size_t)tok * H_DIM + c], wm * acc[am][bn][rg]);
        }
      }
    }
  }
}

extern "C" void kernel_launch(void* const* d_in, const int* in_sizes, int n_in,
                              void* d_out, int out_size, void* d_ws,
                              size_t ws_size, hipStream_t stream) {
  (void)in_sizes; (void)n_in; (void)out_size; (void)ws_size;
  const float* x  = (const float*)d_in[0];
  const float* gw = (const float*)d_in[1];
  const float* lb = (const float*)d_in[2];
  const float* eg = (const float*)d_in[3];
  const float* eu = (const float*)d_in[4];
  const float* ed = (const float*)d_in[5];
  const float* sg = (const float*)d_in[6];
  const float* su = (const float*)d_in[7];
  const float* sd = (const float*)d_in[8];
  float* out = (float*)d_out;
  char* ws = (char*)d_ws;

  int* cnt      = (int*)(ws + WS_CNT);
  float* wsum   = (float*)(ws + WS_WSUM);
  int* lists    = (int*)(ws + WS_LISTS);
  int2* topi    = (int2*)(ws + WS_TOPI);
  float2* topw  = (float2*)(ws + WS_TOPW);
  bf16* act_e   = (bf16*)(ws + WS_ACT_E);
  bf16* act_s   = (bf16*)(ws + WS_ACT_S);

  hipMemsetAsync(d_out, 0, (size_t)NT * H_DIM * sizeof(float), stream);

  router_kernel<<<NT / 4, 256, 0, stream>>>(x, gw, lb, topi, topw);
  build_kernel<<<1, 512, 0, stream>>>(topi, topw, cnt, wsum, lists);
  gateup_kernel<<<dim3(16, 32, 9), 256, 0, stream>>>(x, eg, eu, sg, su, cnt,
                                                     lists, act_e, act_s);
  down_kernel<<<dim3(16, 32, 9), 256, 0, stream>>>(act_e, act_s, ed, sd, cnt,
                                                   wsum, lists, out);
}

// Round 3
// 232.268 us; speedup vs baseline: 1.5138x; 1.1512x over previous
//
#include <hip/hip_runtime.h>

#define H_DIM 1024
#define I_DIM 512
#define NE 8
#define SI_DIM 1024
#define NT 2048
#define NS 4096  // total expert slots = NT * K

typedef __bf16 bf16;
typedef __bf16 bf16x4 __attribute__((ext_vector_type(4)));
typedef __bf16 bf16x8 __attribute__((ext_vector_type(8)));
typedef float f32x4 __attribute__((ext_vector_type(4)));

// ---- bf16 weight buffer element offsets (concat order) ----
#define W_EG 0
#define W_EU (NE * I_DIM * H_DIM)
#define W_ED (2 * NE * I_DIM * H_DIM)
#define W_SG (3 * NE * I_DIM * H_DIM)
#define W_SU (W_SG + SI_DIM * H_DIM)
#define W_SD (W_SU + SI_DIM * H_DIM)
#define W_TOT (W_SD + H_DIM * SI_DIM)  // 15,728,640 elems

// ---- workspace layout (bytes, all 16B-aligned) ----
#define OFF_CNT 0                                  // int[8]
#define OFF_WM 64                                  // float[8]
#define OFF_BASE 128                               // int[9]
#define OFF_TOPI 1024                              // int2[NT]
#define OFF_TOPW (OFF_TOPI + NT * 8)               // float2[NT]
#define OFF_GSLOT (OFF_TOPW + NT * 8)              // int2[NT]
#define OFF_LISTS (OFF_GSLOT + NT * 8)             // int[NS]
#define OFF_WB (OFF_LISTS + NS * 4)                // bf16[W_TOT]
#define OFF_XB (OFF_WB + W_TOT * 2)                // bf16[NT][H]
#define OFF_XG (OFF_XB + NT * H_DIM * 2)           // bf16[NS+128][H]
#define OFF_ACTE (OFF_XG + (NS + 128) * H_DIM * 2) // bf16[NS+128][I]
#define OFF_ACTS (OFF_ACTE + (NS + 128) * I_DIM * 2) // bf16[NT][SI]
#define OFF_YDE (OFF_ACTS + (size_t)NT * SI_DIM * 2) // bf16[NS][H]
#define OFF_YDS (OFF_YDE + (size_t)NS * H_DIM * 2)   // bf16[NT][H]

__device__ __forceinline__ bf16x4 cvt4(f32x4 v) {
  bf16x4 r;
  r.x = (bf16)v.x; r.y = (bf16)v.y; r.z = (bf16)v.z; r.w = (bf16)v.w;
  return r;
}

// async global->LDS, 16B per lane. LDS side must be uniform-base + lane*16.
__device__ __forceinline__ void glds16(const bf16* g, bf16* l) {
  __builtin_amdgcn_global_load_lds(
      (const __attribute__((address_space(1))) unsigned int*)g,
      (__attribute__((address_space(3))) unsigned int*)l, 16, 0, 0);
}

// ---------------- weight convert: fp32 -> bf16, one pass ----------------
__global__ __launch_bounds__(256) void convert_w(
    const float* __restrict__ eg, const float* __restrict__ eu,
    const float* __restrict__ ed, const float* __restrict__ sg,
    const float* __restrict__ su, const float* __restrict__ sd,
    bf16* __restrict__ wb) {
  size_t i = ((size_t)blockIdx.x * 256 + threadIdx.x) * 4;
  if (i >= W_TOT) return;
  const float* src;
  size_t o;
  if (i < W_EU)      { src = eg; o = i - W_EG; }
  else if (i < W_ED) { src = eu; o = i - W_EU; }
  else if (i < W_SG) { src = ed; o = i - W_ED; }
  else if (i < W_SU) { src = sg; o = i - W_SG; }
  else if (i < W_SD) { src = su; o = i - W_SU; }
  else               { src = sd; o = i - W_SD; }
  *(bf16x4*)(wb + i) = cvt4(*(const f32x4*)(src + o));
}

// ---------------- router: one wave per token, no atomics ----------------
__global__ __launch_bounds__(256) void router_kernel(
    const float* __restrict__ x, const float* __restrict__ gw,
    const float* __restrict__ lb, int2* __restrict__ topi,
    float2* __restrict__ topw) {
  const int lane = threadIdx.x & 63;
  const int t = blockIdx.x * 4 + (threadIdx.x >> 6);
  const float* xr = x + (size_t)t * H_DIM;

  float s[NE];
#pragma unroll
  for (int e = 0; e < NE; e++) s[e] = 0.f;
#pragma unroll
  for (int k0 = 0; k0 < H_DIM; k0 += 256) {
    f32x4 xv = *(const f32x4*)(xr + k0 + lane * 4);
#pragma unroll
    for (int e = 0; e < NE; e++) {
      f32x4 gv = *(const f32x4*)(gw + e * H_DIM + k0 + lane * 4);
      s[e] += xv.x * gv.x + xv.y * gv.y + xv.z * gv.z + xv.w * gv.w;
    }
  }
#pragma unroll
  for (int e = 0; e < NE; e++) {
    float v = s[e];
#pragma unroll
    for (int off = 32; off > 0; off >>= 1) v += __shfl_xor(v, off);
    s[e] = v;
  }
  if (lane == 0) {
    float sc[NE];
#pragma unroll
    for (int e = 0; e < NE; e++) sc[e] = 1.f / (1.f + expf(-(s[e] + lb[e])));
    int i1 = 0;
#pragma unroll
    for (int e = 1; e < NE; e++)
      if (sc[e] > sc[i1]) i1 = e;  // strict > : ties -> lowest index
    int i2 = -1;
#pragma unroll
    for (int e = 0; e < NE; e++) {
      if (e == i1) continue;
      if (i2 < 0 || sc[e] > sc[i2]) i2 = e;
    }
    float w1 = sc[i1], w2 = sc[i2];
    float inv = 1.f / (w1 + w2 + 1e-8f);
    topi[t] = make_int2(i1, i2);
    topw[t] = make_float2(w1 * inv, w2 * inv);
  }
}

// ------- build: 1 block, wave e = expert e; compact slots, no atomics -------
__global__ __launch_bounds__(512) void build_kernel(
    const int2* __restrict__ topi, const float2* __restrict__ topw,
    int* __restrict__ cnt, float* __restrict__ wm, int* __restrict__ base,
    int* __restrict__ lists, int2* __restrict__ gslot) {
  __shared__ int cnt_l[NE];
  __shared__ int base_l[NE + 1];
  const int e = threadIdx.x >> 6;
  const int lane = threadIdx.x & 63;

  // phase 1: count + weight sum
  int c = 0;
  float wacc = 0.f;
  for (int t0 = 0; t0 < NT; t0 += 64) {
    int2 ti = topi[t0 + lane];
    float2 tw = topw[t0 + lane];
    bool hit = (ti.x == e) || (ti.y == e);
    float w = (ti.x == e) ? tw.x : ((ti.y == e) ? tw.y : 0.f);
    c += __popcll(__ballot(hit));
#pragma unroll
    for (int off = 32; off > 0; off >>= 1) w += __shfl_xor(w, off);
    wacc += w;
  }
  if (lane == 0) {
    cnt_l[e] = c;
    cnt[e] = c;
    wm[e] = wacc / (float)(c > 0 ? c : 1);
  }
  __syncthreads();
  if (threadIdx.x == 0) {
    int b = 0;
    for (int i = 0; i < NE; i++) {
      base_l[i] = b;
      base[i] = b;
      b += cnt_l[i];
    }
    base_l[NE] = b;
    base[NE] = b;
  }
  __syncthreads();

  // phase 2: place tokens at compact global slots
  int pos = base_l[e];
  for (int t0 = 0; t0 < NT; t0 += 64) {
    int t = t0 + lane;
    int2 ti = topi[t];
    bool hit = (ti.x == e) || (ti.y == e);
    unsigned long long m = __ballot(hit);
    int pre = __popcll(m & ((1ull << lane) - 1ull));
    if (hit) {
      int g = pos + pre;
      lists[g] = t;
      if (ti.x == e) gslot[t].x = g;
      else gslot[t].y = g;
    }
    pos += __popcll(m);
  }
}

// ------- gather: xg[slot] = bf16(x[lists[slot]]); xb = bf16(x) -------
__global__ __launch_bounds__(256) void gather_kernel(
    const float* __restrict__ x, const int* __restrict__ lists,
    bf16* __restrict__ xg, bf16* __restrict__ xb) {
  int b = blockIdx.x;
  const float* src;
  bf16* dst;
  if (b < NS) {
    src = x + (size_t)lists[b] * H_DIM;
    dst = xg + (size_t)b * H_DIM;
  } else {
    int r = b - NS;
    src = x + (size_t)r * H_DIM;
    dst = xb + (size_t)r * H_DIM;
  }
  int c = threadIdx.x * 4;
  *(bf16x4*)(dst + c) = cvt4(*(const f32x4*)(src + c));
}

// ------- fused gate+up GEMM (m97 structure, dual-B) -> silu(g)*u bf16 -------
// grid: (8 colTiles, 16 rowTiles, 9); 128x128 tile, BK=64, K=H=1024
__global__ __launch_bounds__(256, 2) void gemm_gu(
    const bf16* __restrict__ wb, const bf16* __restrict__ xg,
    const bf16* __restrict__ xb, const int* __restrict__ cnt,
    const int* __restrict__ base, bf16* __restrict__ act_e,
    bf16* __restrict__ act_s) {
  const int z = blockIdx.z, colTile = blockIdx.x, rowTile = blockIdx.y;
  const bf16 *Ab, *Gb, *Ub;
  bf16* Cp;
  int ldc, mrem;
  if (z < NE) {
    if (colTile >= I_DIM / 128) return;
    int c = cnt[z];
    if (rowTile * 128 >= c) return;
    int rb = base[z] + rowTile * 128;
    Ab = xg + (size_t)rb * H_DIM;
    Gb = wb + W_EG + (size_t)z * I_DIM * H_DIM + (size_t)colTile * 128 * H_DIM;
    Ub = wb + W_EU + (size_t)z * I_DIM * H_DIM + (size_t)colTile * 128 * H_DIM;
    Cp = act_e + (size_t)rb * I_DIM + colTile * 128;
    ldc = I_DIM;
    mrem = c - rowTile * 128;
  } else {
    Ab = xb + (size_t)rowTile * 128 * H_DIM;
    Gb = wb + W_SG + (size_t)colTile * 128 * H_DIM;
    Ub = wb + W_SU + (size_t)colTile * 128 * H_DIM;
    Cp = act_s + (size_t)rowTile * 128 * SI_DIM + colTile * 128;
    ldc = SI_DIM;
    mrem = 128;
  }

  __shared__ __align__(16) bf16 As[128 * 64];
  __shared__ __align__(16) bf16 Bgs[128 * 64];
  __shared__ __align__(16) bf16 Bus[128 * 64];

  const int tid = threadIdx.x;
  const int lane = tid & 63, wave = tid >> 6;
  const int mw = (wave >> 1) * 64, nw = (wave & 1) * 64;
  const int l15 = lane & 15, quad = lane >> 4;
  const int srow = tid >> 3;       // 0..31
  const int scol = (tid & 7) * 8;  // bf16 elem offset, 16B chunks

  f32x4 ag[4][4] = {};
  f32x4 au[4][4] = {};

  for (int k0 = 0; k0 < H_DIM; k0 += 64) {
#pragma unroll
    for (int r = 0; r < 4; r++) {
      int row = srow + r * 32;
      glds16(Ab + (size_t)row * H_DIM + k0 + scol, &As[row * 64 + scol]);
    }
#pragma unroll
    for (int r = 0; r < 4; r++) {
      int row = srow + r * 32;
      glds16(Gb + (size_t)row * H_DIM + k0 + scol, &Bgs[row * 64 + scol]);
    }
#pragma unroll
    for (int r = 0; r < 4; r++) {
      int row = srow + r * 32;
      glds16(Ub + (size_t)row * H_DIM + k0 + scol, &Bus[row * 64 + scol]);
    }
    __syncthreads();
#pragma unroll
    for (int kk = 0; kk < 2; kk++) {
      const int kof = kk * 32 + quad * 8;
      bf16x8 av[4], gv[4], uv[4];
#pragma unroll
      for (int i = 0; i < 4; i++) {
        av[i] = *(const bf16x8*)&As[(mw + i * 16 + l15) * 64 + kof];
        gv[i] = *(const bf16x8*)&Bgs[(nw + i * 16 + l15) * 64 + kof];
        uv[i] = *(const bf16x8*)&Bus[(nw + i * 16 + l15) * 64 + kof];
      }
#pragma unroll
      for (int i = 0; i < 4; i++)
#pragma unroll
        for (int j = 0; j < 4; j++) {
          ag[i][j] = __builtin_amdgcn_mfma_f32_16x16x32_bf16(av[i], gv[j], ag[i][j], 0, 0, 0);
          au[i][j] = __builtin_amdgcn_mfma_f32_16x16x32_bf16(av[i], uv[j], au[i][j], 0, 0, 0);
        }
    }
    __syncthreads();
  }

#pragma unroll
  for (int i = 0; i < 4; i++) {
#pragma unroll
    for (int rg = 0; rg < 4; rg++) {
      int rl = mw + i * 16 + quad * 4 + rg;
      if (rl < mrem) {
#pragma unroll
        for (int j = 0; j < 4; j++) {
          int c = nw + j * 16 + l15;
          float g = ag[i][j][rg], u = au[i][j][rg];
          Cp[(size_t)rl * ldc + c] = (bf16)((g / (1.f + __expf(-g))) * u);
        }
      }
    }
  }
}

// ------- down GEMM: yd = act @ Wd^T (bf16 out, no atomics) -------
// grid: (8 colTiles over H, 16 rowTiles, 9)
__global__ __launch_bounds__(256, 2) void gemm_down(
    const bf16* __restrict__ wb, const bf16* __restrict__ act_e,
    const bf16* __restrict__ act_s, const int* __restrict__ cnt,
    const int* __restrict__ base, bf16* __restrict__ yd_e,
    bf16* __restrict__ yd_s) {
  const int z = blockIdx.z, colTile = blockIdx.x, rowTile = blockIdx.y;
  const bf16 *Ab, *Bb;
  bf16* Cp;
  int K, mrem;
  if (z < NE) {
    int c = cnt[z];
    if (rowTile * 128 >= c) return;
    int rb = base[z] + rowTile * 128;
    Ab = act_e + (size_t)rb * I_DIM;
    K = I_DIM;
    Bb = wb + W_ED + (size_t)z * H_DIM * I_DIM + (size_t)colTile * 128 * I_DIM;
    Cp = yd_e + (size_t)rb * H_DIM + colTile * 128;
    mrem = c - rowTile * 128;
  } else {
    Ab = act_s + (size_t)rowTile * 128 * SI_DIM;
    K = SI_DIM;
    Bb = wb + W_SD + (size_t)colTile * 128 * SI_DIM;
    Cp = yd_s + (size_t)rowTile * 128 * H_DIM + colTile * 128;
    mrem = 128;
  }

  __shared__ __align__(16) bf16 As[128 * 64];
  __shared__ __align__(16) bf16 Bs[128 * 64];

  const int tid = threadIdx.x;
  const int lane = tid & 63, wave = tid >> 6;
  const int mw = (wave >> 1) * 64, nw = (wave & 1) * 64;
  const int l15 = lane & 15, quad = lane >> 4;
  const int srow = tid >> 3;
  const int scol = (tid & 7) * 8;

  f32x4 acc[4][4] = {};

  for (int k0 = 0; k0 < K; k0 += 64) {
#pragma unroll
    for (int r = 0; r < 4; r++) {
      int row = srow + r * 32;
      glds16(Ab + (size_t)row * K + k0 + scol, &As[row * 64 + scol]);
    }
#pragma unroll
    for (int r = 0; r < 4; r++) {
      int row = srow + r * 32;
      glds16(Bb + (size_t)row * K + k0 + scol, &Bs[row * 64 + scol]);
    }
    __syncthreads();
#pragma unroll
    for (int kk = 0; kk < 2; kk++) {
      const int kof = kk * 32 + quad * 8;
      bf16x8 av[4], bv[4];
#pragma unroll
      for (int i = 0; i < 4; i++) {
        av[i] = *(const bf16x8*)&As[(mw + i * 16 + l15) * 64 + kof];
        bv[i] = *(const bf16x8*)&Bs[(nw + i * 16 + l15) * 64 + kof];
      }
#pragma unroll
      for (int i = 0; i < 4; i++)
#pragma unroll
        for (int j = 0; j < 4; j++)
          acc[i][j] = __builtin_amdgcn_mfma_f32_16x16x32_bf16(av[i], bv[j], acc[i][j], 0, 0, 0);
    }
    __syncthreads();
  }

#pragma unroll
  for (int i = 0; i < 4; i++) {
#pragma unroll
    for (int rg = 0; rg < 4; rg++) {
      int rl = mw + i * 16 + quad * 4 + rg;
      if (rl < mrem) {
#pragma unroll
        for (int j = 0; j < 4; j++) {
          int c = nw + j * 16 + l15;
          Cp[(size_t)rl * H_DIM + c] = (bf16)acc[i][j][rg];
        }
      }
    }
  }
}

// ------- combine: out[t] = wm[e1]*yd[g1] + wm[e2]*yd[g2] + yd_s[t] -------
__global__ __launch_bounds__(256) void combine_kernel(
    const bf16* __restrict__ yd_e, const bf16* __restrict__ yd_s,
    const int2* __restrict__ topi, const int2* __restrict__ gslot,
    const float* __restrict__ wm, float* __restrict__ out) {
  int t = blockIdx.x;
  int2 ei = topi[t];
  int2 gi = gslot[t];
  float w1 = wm[ei.x], w2 = wm[ei.y];
  int c = threadIdx.x * 4;
  bf16x4 y1 = *(const bf16x4*)(yd_e + (size_t)gi.x * H_DIM + c);
  bf16x4 y2 = *(const bf16x4*)(yd_e + (size_t)gi.y * H_DIM + c);
  bf16x4 ys = *(const bf16x4*)(yd_s + (size_t)t * H_DIM + c);
  f32x4 o;
  o.x = w1 * (float)y1.x + w2 * (float)y2.x + (float)ys.x;
  o.y = w1 * (float)y1.y + w2 * (float)y2.y + (float)ys.y;
  o.z = w1 * (float)y1.z + w2 * (float)y2.z + (float)ys.z;
  o.w = w1 * (float)y1.w + w2 * (float)y2.w + (float)ys.w;
  *(f32x4*)(out + (size_t)t * H_DIM + c) = o;
}

extern "C" void kernel_launch(void* const* d_in, const int* in_sizes, int n_in,
                              void* d_out, int out_size, void* d_ws,
                              size_t ws_size, hipStream_t stream) {
  (void)in_sizes; (void)n_in; (void)out_size; (void)ws_size;
  const float* x  = (const float*)d_in[0];
  const float* gw = (const float*)d_in[1];
  const float* lb = (const float*)d_in[2];
  const float* eg = (const float*)d_in[3];
  const float* eu = (const float*)d_in[4];
  const float* ed = (const float*)d_in[5];
  const float* sg = (const float*)d_in[6];
  const float* su = (const float*)d_in[7];
  const float* sd = (const float*)d_in[8];
  float* out = (float*)d_out;
  char* ws = (char*)d_ws;

  int* cnt     = (int*)(ws + OFF_CNT);
  float* wm    = (float*)(ws + OFF_WM);
  int* base    = (int*)(ws + OFF_BASE);
  int2* topi   = (int2*)(ws + OFF_TOPI);
  float2* topw = (float2*)(ws + OFF_TOPW);
  int2* gslot  = (int2*)(ws + OFF_GSLOT);
  int* lists   = (int*)(ws + OFF_LISTS);
  bf16* wb     = (bf16*)(ws + OFF_WB);
  bf16* xb     = (bf16*)(ws + OFF_XB);
  bf16* xg     = (bf16*)(ws + OFF_XG);
  bf16* act_e  = (bf16*)(ws + OFF_ACTE);
  bf16* act_s  = (bf16*)(ws + OFF_ACTS);
  bf16* yd_e   = (bf16*)(ws + OFF_YDE);
  bf16* yd_s   = (bf16*)(ws + OFF_YDS);

  convert_w<<<W_TOT / 1024, 256, 0, stream>>>(eg, eu, ed, sg, su, sd, wb);
  router_kernel<<<NT / 4, 256, 0, stream>>>(x, gw, lb, topi, topw);
  build_kernel<<<1, 512, 0, stream>>>(topi, topw, cnt, wm, base, lists, gslot);
  gather_kernel<<<NS + NT, 256, 0, stream>>>(x, lists, xg, xb);
  gemm_gu<<<dim3(8, 16, 9), 256, 0, stream>>>(wb, xg, xb, cnt, base, act_e, act_s);
  gemm_down<<<dim3(8, 16, 9), 256, 0, stream>>>(wb, act_e, act_s, cnt, base, yd_e, yd_s);
  combine_kernel<<<NT, 256, 0, stream>>>(yd_e, yd_s, topi, gslot, wm, out);
}

// Round 4
// 224.931 us; speedup vs baseline: 1.5632x; 1.0326x over previous
//
#include <hip/hip_runtime.h>

#define H_DIM 1024
#define I_DIM 512
#define NE 8
#define SI_DIM 1024
#define NT 2048
#define NS 4096  // total expert slots = NT * K

typedef __bf16 bf16;
typedef __bf16 bf16x4 __attribute__((ext_vector_type(4)));
typedef __bf16 bf16x8 __attribute__((ext_vector_type(8)));
typedef float f32x4 __attribute__((ext_vector_type(4)));

// ---- bf16 weight buffer element offsets ----
// W_GU: per expert, 1024 rows interleaved by 16 (gate16,up16,...), K=H contig
// W_DN: per expert, H rows x I(K), straight
// W_SGU: shared, 2048 rows interleaved by 16, K=H
// W_SDN: shared, H rows x SI(K), straight
#define W_GU 0
#define W_DN 8388608ull
#define W_SGU 12582912ull
#define W_SDN 14680064ull
#define W_TOT 15728640ull

// prep grid split
#define NWB 15360  // W_TOT/1024 weight-convert blocks
#define NXB 2048   // NT*H/1024 x-convert blocks
#define NRB 512    // NT/4 router blocks

// ---- workspace layout (bytes, 16B-aligned) ----
#define OFF_CNT 0
#define OFF_WM 64
#define OFF_BASE 128
#define OFF_TOPI 1024
#define OFF_TOPW (OFF_TOPI + NT * 8)
#define OFF_GSLOT (OFF_TOPW + NT * 8)
#define OFF_LISTS (OFF_GSLOT + NT * 8)
#define OFF_WB (OFF_LISTS + NS * 4)                   // bf16[W_TOT]
#define OFF_XB (OFF_WB + W_TOT * 2)                   // bf16[NT][H]
#define OFF_ACTE (OFF_XB + (size_t)NT * H_DIM * 2)    // bf16[NS+128][I]
#define OFF_ACTS (OFF_ACTE + (size_t)(NS + 128) * I_DIM * 2)  // bf16[NT][SI]
#define OFF_YDE (OFF_ACTS + (size_t)NT * SI_DIM * 2)  // bf16[NS][H]
#define OFF_YDS (OFF_YDE + (size_t)NS * H_DIM * 2)    // bf16[NT][H]

__device__ __forceinline__ bf16x4 cvt4(f32x4 v) {
  bf16x4 r;
  r.x = (bf16)v.x; r.y = (bf16)v.y; r.z = (bf16)v.z; r.w = (bf16)v.w;
  return r;
}

__device__ __forceinline__ void glds16(const bf16* g, bf16* l) {
  __builtin_amdgcn_global_load_lds(
      (const __attribute__((address_space(1))) unsigned int*)g,
      (__attribute__((address_space(3))) unsigned int*)l, 16, 0, 0);
}

// ---- prep: weight convert (interleaved) + x convert + router, one kernel ----
__global__ __launch_bounds__(256) void prep_kernel(
    const float* __restrict__ x, const float* __restrict__ gw,
    const float* __restrict__ lb, const float* __restrict__ eg,
    const float* __restrict__ eu, const float* __restrict__ ed,
    const float* __restrict__ sg, const float* __restrict__ su,
    const float* __restrict__ sd, bf16* __restrict__ wb,
    bf16* __restrict__ xb, int2* __restrict__ topi,
    float2* __restrict__ topw) {
  const int bx = blockIdx.x;
  const int tid = threadIdx.x;
  if (bx < NWB) {
    size_t i = ((size_t)bx * 256 + tid) * 4;
    const float* src;
    if (i < W_DN) {  // expert gate/up, interleaved by 16 rows
      size_t z = i >> 20;
      int rem = (int)(i & ((1u << 20) - 1));
      int rp = rem >> 10, k = rem & 1023;
      int b = rp >> 4;
      int sr = ((b >> 1) << 4) | (rp & 15);
      src = ((b & 1) ? eu : eg) + (z << 19) + ((size_t)sr << 10) + k;
    } else if (i < W_SGU) {  // expert down, straight
      src = ed + (i - W_DN);
    } else if (i < W_SDN) {  // shared gate/up, interleaved
      int rem = (int)(i - W_SGU);
      int rp = rem >> 10, k = rem & 1023;
      int b = rp >> 4;
      int sr = ((b >> 1) << 4) | (rp & 15);
      src = ((b & 1) ? su : sg) + ((size_t)sr << 10) + k;
    } else {  // shared down, straight
      src = sd + (i - W_SDN);
    }
    *(bf16x4*)(wb + i) = cvt4(*(const f32x4*)src);
  } else if (bx < NWB + NXB) {
    size_t i = ((size_t)(bx - NWB) * 256 + tid) * 4;
    *(bf16x4*)(xb + i) = cvt4(*(const f32x4*)(x + i));
  } else {
    const int lane = tid & 63;
    const int t = (bx - NWB - NXB) * 4 + (tid >> 6);
    const float* xr = x + (size_t)t * H_DIM;
    float s[NE];
#pragma unroll
    for (int e = 0; e < NE; e++) s[e] = 0.f;
#pragma unroll
    for (int k0 = 0; k0 < H_DIM; k0 += 256) {
      f32x4 xv = *(const f32x4*)(xr + k0 + lane * 4);
#pragma unroll
      for (int e = 0; e < NE; e++) {
        f32x4 gv = *(const f32x4*)(gw + e * H_DIM + k0 + lane * 4);
        s[e] += xv.x * gv.x + xv.y * gv.y + xv.z * gv.z + xv.w * gv.w;
      }
    }
#pragma unroll
    for (int e = 0; e < NE; e++) {
      float v = s[e];
#pragma unroll
      for (int off = 32; off > 0; off >>= 1) v += __shfl_xor(v, off);
      s[e] = v;
    }
    if (lane == 0) {
      float sc[NE];
#pragma unroll
      for (int e = 0; e < NE; e++) sc[e] = 1.f / (1.f + expf(-(s[e] + lb[e])));
      int i1 = 0;
#pragma unroll
      for (int e = 1; e < NE; e++)
        if (sc[e] > sc[i1]) i1 = e;  // strict > : ties -> lowest index
      int i2 = -1;
#pragma unroll
      for (int e = 0; e < NE; e++) {
        if (e == i1) continue;
        if (i2 < 0 || sc[e] > sc[i2]) i2 = e;
      }
      float w1 = sc[i1], w2 = sc[i2];
      float inv = 1.f / (w1 + w2 + 1e-8f);
      topi[t] = make_int2(i1, i2);
      topw[t] = make_float2(w1 * inv, w2 * inv);
    }
  }
}

// ------- build: 1 block, wave e = expert e; compact slots, no atomics -------
__global__ __launch_bounds__(512) void build_kernel(
    const int2* __restrict__ topi, const float2* __restrict__ topw,
    int* __restrict__ cnt, float* __restrict__ wm, int* __restrict__ base,
    int* __restrict__ lists, int2* __restrict__ gslot) {
  __shared__ int cnt_l[NE];
  __shared__ int base_l[NE + 1];
  const int e = threadIdx.x >> 6;
  const int lane = threadIdx.x & 63;

  int c = 0;
  float wacc = 0.f;
  for (int t0 = 0; t0 < NT; t0 += 64) {
    int2 ti = topi[t0 + lane];
    float2 tw = topw[t0 + lane];
    bool hit = (ti.x == e) || (ti.y == e);
    float w = (ti.x == e) ? tw.x : ((ti.y == e) ? tw.y : 0.f);
    c += __popcll(__ballot(hit));
#pragma unroll
    for (int off = 32; off > 0; off >>= 1) w += __shfl_xor(w, off);
    wacc += w;
  }
  if (lane == 0) {
    cnt_l[e] = c;
    cnt[e] = c;
    wm[e] = wacc / (float)(c > 0 ? c : 1);
  }
  __syncthreads();
  if (threadIdx.x == 0) {
    int b = 0;
    for (int i = 0; i < NE; i++) {
      base_l[i] = b;
      base[i] = b;
      b += cnt_l[i];
    }
    base[NE] = b;
  }
  __syncthreads();

  int pos = base_l[e];
  for (int t0 = 0; t0 < NT; t0 += 64) {
    int t = t0 + lane;
    int2 ti = topi[t];
    bool hit = (ti.x == e) || (ti.y == e);
    unsigned long long m = __ballot(hit);
    int pre = __popcll(m & ((1ull << lane) - 1ull));
    if (hit) {
      int g = pos + pre;
      lists[g] = t;
      if (ti.x == e) gslot[t].x = g;
      else gslot[t].y = g;
    }
    pos += __popcll(m);
  }
}

// ------- gate+up GEMM over interleaved B; epilogue silu(g)*u -> bf16 act ----
// grid: (16 colTiles, 16 rowTiles, 9); 128x128 tile, BK=64
__global__ __launch_bounds__(256, 2) void gemm_gu(
    const bf16* __restrict__ wb, const bf16* __restrict__ xb,
    const int* __restrict__ cnt, const int* __restrict__ base,
    const int* __restrict__ lists, bf16* __restrict__ act_e,
    bf16* __restrict__ act_s) {
  const int z = blockIdx.z, ct = blockIdx.x, rt = blockIdx.y;
  const bf16* Bb;
  bf16* Cb;
  int mrem, ldc;
  __shared__ int rows_s[128];
  __shared__ __align__(16) bf16 As[128 * 64];
  __shared__ __align__(16) bf16 Bs[128 * 64];
  const int tid = threadIdx.x;
  if (z < NE) {
    if (ct >= 8) return;
    int c = cnt[z];
    if (rt * 128 >= c) return;
    int rb = base[z] + rt * 128;
    mrem = c - rt * 128;
    if (tid < 128) rows_s[tid] = lists[rb + (tid < mrem ? tid : mrem - 1)];
    Bb = wb + W_GU + ((size_t)z << 20) + (size_t)ct * 128 * H_DIM;
    Cb = act_e + (size_t)rb * I_DIM;
    ldc = I_DIM;
  } else {
    mrem = 128;
    if (tid < 128) rows_s[tid] = rt * 128 + tid;
    Bb = wb + W_SGU + (size_t)ct * 128 * H_DIM;
    Cb = act_s + (size_t)rt * 128 * SI_DIM;
    ldc = SI_DIM;
  }
  __syncthreads();

  const int lane = tid & 63, wave = tid >> 6;
  const int mw = (wave >> 1) * 64, nw = (wave & 1) * 64;
  const int l15 = lane & 15, quad = lane >> 4;
  const int srow = tid >> 3, scol = (tid & 7) * 8;

  const bf16* ap[4];
  const bf16* bp[4];
#pragma unroll
  for (int r = 0; r < 4; r++) {
    ap[r] = xb + (size_t)rows_s[srow + r * 32] * H_DIM + scol;
    bp[r] = Bb + (size_t)(srow + r * 32) * H_DIM + scol;
  }

  f32x4 acc[4][4] = {};
  for (int k0 = 0; k0 < H_DIM; k0 += 64) {
#pragma unroll
    for (int r = 0; r < 4; r++)
      glds16(ap[r] + k0, &As[(srow + r * 32) * 64 + scol]);
#pragma unroll
    for (int r = 0; r < 4; r++)
      glds16(bp[r] + k0, &Bs[(srow + r * 32) * 64 + scol]);
    __syncthreads();
#pragma unroll
    for (int kk = 0; kk < 2; kk++) {
      const int kof = kk * 32 + quad * 8;
      bf16x8 av[4], bv[4];
#pragma unroll
      for (int i = 0; i < 4; i++) {
        av[i] = *(const bf16x8*)&As[(mw + i * 16 + l15) * 64 + kof];
        bv[i] = *(const bf16x8*)&Bs[(nw + i * 16 + l15) * 64 + kof];
      }
#pragma unroll
      for (int i = 0; i < 4; i++)
#pragma unroll
        for (int j = 0; j < 4; j++)
          acc[i][j] = __builtin_amdgcn_mfma_f32_16x16x32_bf16(av[i], bv[j], acc[i][j], 0, 0, 0);
    }
    __syncthreads();
  }

  // j even = gate cols, j odd = up cols of the same 16-col group (same lane/reg)
#pragma unroll
  for (int i = 0; i < 4; i++) {
#pragma unroll
    for (int rg = 0; rg < 4; rg++) {
      int rl = mw + i * 16 + quad * 4 + rg;
      if (rl < mrem) {
#pragma unroll
        for (int jp = 0; jp < 2; jp++) {
          float g = acc[i][jp * 2][rg];
          float u = acc[i][jp * 2 + 1][rg];
          int c = ct * 64 + (nw >> 1) + jp * 16 + l15;
          Cb[(size_t)rl * ldc + c] = (bf16)((g / (1.f + __expf(-g))) * u);
        }
      }
    }
  }
}

// ------- down GEMM: yd = act @ Wd^T (bf16 out) -------
// grid: (8 colTiles over H, 16 rowTiles, 9)
__global__ __launch_bounds__(256, 2) void gemm_down(
    const bf16* __restrict__ wb, const bf16* __restrict__ act_e,
    const bf16* __restrict__ act_s, const int* __restrict__ cnt,
    const int* __restrict__ base, bf16* __restrict__ yd_e,
    bf16* __restrict__ yd_s) {
  const int z = blockIdx.z, ct = blockIdx.x, rt = blockIdx.y;
  const bf16 *Ab, *Bb;
  bf16* Cb;
  int K, mrem;
  if (z < NE) {
    int c = cnt[z];
    if (rt * 128 >= c) return;
    int rb = base[z] + rt * 128;
    mrem = c - rt * 128;
    Ab = act_e + (size_t)rb * I_DIM;
    K = I_DIM;
    Bb = wb + W_DN + ((size_t)z << 19) + (size_t)ct * 128 * I_DIM;
    Cb = yd_e + (size_t)rb * H_DIM + ct * 128;
  } else {
    mrem = 128;
    Ab = act_s + (size_t)rt * 128 * SI_DIM;
    K = SI_DIM;
    Bb = wb + W_SDN + (size_t)ct * 128 * SI_DIM;
    Cb = yd_s + (size_t)rt * 128 * H_DIM + ct * 128;
  }

  __shared__ __align__(16) bf16 As[128 * 64];
  __shared__ __align__(16) bf16 Bs[128 * 64];

  const int tid = threadIdx.x;
  const int lane = tid & 63, wave = tid >> 6;
  const int mw = (wave >> 1) * 64, nw = (wave & 1) * 64;
  const int l15 = lane & 15, quad = lane >> 4;
  const int srow = tid >> 3, scol = (tid & 7) * 8;

  f32x4 acc[4][4] = {};
  for (int k0 = 0; k0 < K; k0 += 64) {
#pragma unroll
    for (int r = 0; r < 4; r++)
      glds16(Ab + (size_t)(srow + r * 32) * K + k0 + scol,
             &As[(srow + r * 32) * 64 + scol]);
#pragma unroll
    for (int r = 0; r < 4; r++)
      glds16(Bb + (size_t)(srow + r * 32) * K + k0 + scol,
             &Bs[(srow + r * 32) * 64 + scol]);
    __syncthreads();
#pragma unroll
    for (int kk = 0; kk < 2; kk++) {
      const int kof = kk * 32 + quad * 8;
      bf16x8 av[4], bv[4];
#pragma unroll
      for (int i = 0; i < 4; i++) {
        av[i] = *(const bf16x8*)&As[(mw + i * 16 + l15) * 64 + kof];
        bv[i] = *(const bf16x8*)&Bs[(nw + i * 16 + l15) * 64 + kof];
      }
#pragma unroll
      for (int i = 0; i < 4; i++)
#pragma unroll
        for (int j = 0; j < 4; j++)
          acc[i][j] = __builtin_amdgcn_mfma_f32_16x16x32_bf16(av[i], bv[j], acc[i][j], 0, 0, 0);
    }
    __syncthreads();
  }

#pragma unroll
  for (int i = 0; i < 4; i++) {
#pragma unroll
    for (int rg = 0; rg < 4; rg++) {
      int rl = mw + i * 16 + quad * 4 + rg;
      if (rl < mrem) {
#pragma unroll
        for (int j = 0; j < 4; j++)
          Cb[(size_t)rl * H_DIM + nw + j * 16 + l15] = (bf16)acc[i][j][rg];
      }
    }
  }
}

// ------- combine: out[t] = wm[e1]*yd[g1] + wm[e2]*yd[g2] + yd_s[t] -------
__global__ __launch_bounds__(256) void combine_kernel(
    const bf16* __restrict__ yd_e, const bf16* __restrict__ yd_s,
    const int2* __restrict__ topi, const int2* __restrict__ gslot,
    const float* __restrict__ wm, float* __restrict__ out) {
  int t = blockIdx.x;
  int2 ei = topi[t];
  int2 gi = gslot[t];
  float w1 = wm[ei.x], w2 = wm[ei.y];
  int c = threadIdx.x * 4;
  bf16x4 y1 = *(const bf16x4*)(yd_e + (size_t)gi.x * H_DIM + c);
  bf16x4 y2 = *(const bf16x4*)(yd_e + (size_t)gi.y * H_DIM + c);
  bf16x4 ys = *(const bf16x4*)(yd_s + (size_t)t * H_DIM + c);
  f32x4 o;
  o.x = w1 * (float)y1.x + w2 * (float)y2.x + (float)ys.x;
  o.y = w1 * (float)y1.y + w2 * (float)y2.y + (float)ys.y;
  o.z = w1 * (float)y1.z + w2 * (float)y2.z + (float)ys.z;
  o.w = w1 * (float)y1.w + w2 * (float)y2.w + (float)ys.w;
  *(f32x4*)(out + (size_t)t * H_DIM + c) = o;
}

extern "C" void kernel_launch(void* const* d_in, const int* in_sizes, int n_in,
                              void* d_out, int out_size, void* d_ws,
                              size_t ws_size, hipStream_t stream) {
  (void)in_sizes; (void)n_in; (void)out_size; (void)ws_size;
  const float* x  = (const float*)d_in[0];
  const float* gw = (const float*)d_in[1];
  const float* lb = (const float*)d_in[2];
  const float* eg = (const float*)d_in[3];
  const float* eu = (const float*)d_in[4];
  const float* ed = (const float*)d_in[5];
  const float* sg = (const float*)d_in[6];
  const float* su = (const float*)d_in[7];
  const float* sd = (const float*)d_in[8];
  float* out = (float*)d_out;
  char* ws = (char*)d_ws;

  int* cnt     = (int*)(ws + OFF_CNT);
  float* wm    = (float*)(ws + OFF_WM);
  int* base    = (int*)(ws + OFF_BASE);
  int2* topi   = (int2*)(ws + OFF_TOPI);
  float2* topw = (float2*)(ws + OFF_TOPW);
  int2* gslot  = (int2*)(ws + OFF_GSLOT);
  int* lists   = (int*)(ws + OFF_LISTS);
  bf16* wb     = (bf16*)(ws + OFF_WB);
  bf16* xb     = (bf16*)(ws + OFF_XB);
  bf16* act_e  = (bf16*)(ws + OFF_ACTE);
  bf16* act_s  = (bf16*)(ws + OFF_ACTS);
  bf16* yd_e   = (bf16*)(ws + OFF_YDE);
  bf16* yd_s   = (bf16*)(ws + OFF_YDS);

  prep_kernel<<<NWB + NXB + NRB, 256, 0, stream>>>(x, gw, lb, eg, eu, ed, sg,
                                                   su, sd, wb, xb, topi, topw);
  build_kernel<<<1, 512, 0, stream>>>(topi, topw, cnt, wm, base, lists, gslot);
  gemm_gu<<<dim3(16, 16, 9), 256, 0, stream>>>(wb, xb, cnt, base, lists, act_e,
                                               act_s);
  gemm_down<<<dim3(8, 16, 9), 256, 0, stream>>>(wb, act_e, act_s, cnt, base,
                                                yd_e, yd_s);
  combine_kernel<<<NT, 256, 0, stream>>>(yd_e, yd_s, topi, gslot, wm, out);
}

// Round 8
// 209.554 us; speedup vs baseline: 1.6779x; 1.0734x over previous
//
#include <hip/hip_runtime.h>

#define H_DIM 1024
#define I_DIM 512
#define NE 8
#define SI_DIM 1024
#define NT 2048
#define NS 4096

typedef __bf16 bf16;
typedef __bf16 bf16x4 __attribute__((ext_vector_type(4)));
typedef __bf16 bf16x8 __attribute__((ext_vector_type(8)));
typedef float f32x4 __attribute__((ext_vector_type(4)));

// ---- workspace (bytes, 16B aligned) ----
// NOTE (R8 root-cause fix): lists uses FIXED per-expert regions of NT ints
// (lists[e*NT + i]) => region must be NE*NT*4 bytes. R5-R7 sized it NS*4
// (compact layout leftover) => build_kernel overran 48KB into the next
// buffer (wb/xb), corrupting weights/tokens. absmax R5==R7 fingerprinted it.
#define OFF_CNT 0
#define OFF_WM 64
#define OFF_TOPI 1024
#define OFF_TOPW (OFF_TOPI + NT * 8)
#define OFF_LISTS (OFF_TOPW + NT * 8)
#define OFF_XB (OFF_LISTS + NE * NT * 4)                  // bf16[NT][H]
#define OFF_ACTE (OFF_XB + (size_t)NT * H_DIM * 2)        // bf16[NE][NT][I]
#define OFF_ACTS (OFF_ACTE + (size_t)NE * NT * I_DIM * 2) // bf16[NT][SI]

__device__ __forceinline__ bf16x4 cvt4(f32x4 v) {
  bf16x4 r;
  r.x = (bf16)v.x; r.y = (bf16)v.y; r.z = (bf16)v.z; r.w = (bf16)v.w;
  return r;
}

__device__ __forceinline__ bf16x8 cvt8(f32x4 a, f32x4 b) {
  bf16x8 r;
  r[0] = (bf16)a.x; r[1] = (bf16)a.y; r[2] = (bf16)a.z; r[3] = (bf16)a.w;
  r[4] = (bf16)b.x; r[5] = (bf16)b.y; r[6] = (bf16)b.z; r[7] = (bf16)b.w;
  return r;
}

__device__ __forceinline__ void glds16(const bf16* g, bf16* l) {
  __builtin_amdgcn_global_load_lds(
      (const __attribute__((address_space(1))) unsigned int*)g,
      (__attribute__((address_space(3))) unsigned int*)l, 16, 0, 0);
}

// ---- router + x fp32->bf16 convert (x is read anyway; write xb for free) ----
__global__ __launch_bounds__(256) void router_kernel(
    const float* __restrict__ x, const float* __restrict__ gw,
    const float* __restrict__ lb, bf16* __restrict__ xb,
    int2* __restrict__ topi, float2* __restrict__ topw) {
  const int lane = threadIdx.x & 63;
  const int t = blockIdx.x * 4 + (threadIdx.x >> 6);
  const float* xr = x + (size_t)t * H_DIM;
  bf16* xw = xb + (size_t)t * H_DIM;

  float s[NE];
#pragma unroll
  for (int e = 0; e < NE; e++) s[e] = 0.f;
#pragma unroll
  for (int k0 = 0; k0 < H_DIM; k0 += 256) {
    f32x4 xv = *(const f32x4*)(xr + k0 + lane * 4);
    *(bf16x4*)(xw + k0 + lane * 4) = cvt4(xv);
#pragma unroll
    for (int e = 0; e < NE; e++) {
      f32x4 gv = *(const f32x4*)(gw + e * H_DIM + k0 + lane * 4);
      s[e] += xv.x * gv.x + xv.y * gv.y + xv.z * gv.z + xv.w * gv.w;
    }
  }
#pragma unroll
  for (int e = 0; e < NE; e++) {
    float v = s[e];
#pragma unroll
    for (int off = 32; off > 0; off >>= 1) v += __shfl_xor(v, off);
    s[e] = v;
  }
  if (lane == 0) {
    float sc[NE];
#pragma unroll
    for (int e = 0; e < NE; e++) sc[e] = 1.f / (1.f + expf(-(s[e] + lb[e])));
    int i1 = 0;
#pragma unroll
    for (int e = 1; e < NE; e++)
      if (sc[e] > sc[i1]) i1 = e;  // ties -> lowest index (lax.top_k)
    int i2 = -1;
#pragma unroll
    for (int e = 0; e < NE; e++) {
      if (e == i1) continue;
      if (i2 < 0 || sc[e] > sc[i2]) i2 = e;
    }
    float w1 = sc[i1], w2 = sc[i2];
    float inv = 1.f / (w1 + w2 + 1e-8f);
    topi[t] = make_int2(i1, i2);
    topw[t] = make_float2(w1 * inv, w2 * inv);
  }
}

// ---- build: 8 blocks (one per expert), fixed slot regions, no atomics ----
__global__ __launch_bounds__(256) void build_kernel(
    const int2* __restrict__ topi, const float2* __restrict__ topw,
    int* __restrict__ cnt, float* __restrict__ wm, int* __restrict__ lists) {
  const int e = blockIdx.x;
  const int wave = threadIdx.x >> 6, lane = threadIdx.x & 63;
  __shared__ int wc[4];
  __shared__ float wf[4];
  const int tbeg = wave * (NT / 4), tend = tbeg + NT / 4;

  int c = 0;
  float wa = 0.f;
  for (int t0 = tbeg; t0 < tend; t0 += 64) {
    int2 ti = topi[t0 + lane];
    float2 tw = topw[t0 + lane];
    bool hit = (ti.x == e) || (ti.y == e);
    float w = (ti.x == e) ? tw.x : ((ti.y == e) ? tw.y : 0.f);
    c += __popcll(__ballot(hit));
#pragma unroll
    for (int off = 32; off > 0; off >>= 1) w += __shfl_xor(w, off);
    wa += w;
  }
  if (lane == 0) { wc[wave] = c; wf[wave] = wa; }
  __syncthreads();
  int pos = 0;
  for (int w = 0; w < wave; w++) pos += wc[w];
  for (int t0 = tbeg; t0 < tend; t0 += 64) {
    int t = t0 + lane;
    int2 ti = topi[t];
    bool hit = (ti.x == e) || (ti.y == e);
    unsigned long long m = __ballot(hit);
    int pre = __popcll(m & ((1ull << lane) - 1ull));
    if (hit) lists[e * NT + pos + pre] = t;
    pos += __popcll(m);
  }
  if (threadIdx.x == 0) {
    int ctot = wc[0] + wc[1] + wc[2] + wc[3];
    cnt[e] = ctot;
    wm[e] = (wf[0] + wf[1] + wf[2] + wf[3]) / (float)(ctot > 0 ? ctot : 1);
  }
}

// ---- gate+up GEMM: A=xb via glds16 (swizzled src chunk), B=fp32 weights
// converted in-staging with swizzled ds_write. On-the-fly gate/up interleave.
// grid (16,16,9); experts use ct<8 (N=1024 interleaved), shared ct<16.
__global__ __launch_bounds__(256, 2) void gemm_gu(
    const float* __restrict__ eg, const float* __restrict__ eu,
    const float* __restrict__ sg, const float* __restrict__ su,
    const bf16* __restrict__ xb, const int* __restrict__ cnt,
    const int* __restrict__ lists, bf16* __restrict__ act_e,
    bf16* __restrict__ act_s) {
  const int z = blockIdx.z, ct = blockIdx.x, rt = blockIdx.y;
  const int tid = threadIdx.x;
  __shared__ int rows_s[128];
  __shared__ __align__(16) bf16 As[128 * 64];
  __shared__ __align__(16) bf16 Bs[128 * 64];
  int mrem, ldc;
  bf16* Cb;
  const float *Pg, *Pu;
  if (z < NE) {
    if (ct >= 8) return;
    int c = cnt[z];
    if (rt * 128 >= c) return;
    mrem = c - rt * 128;
    if (tid < 128)
      rows_s[tid] = lists[z * NT + rt * 128 + (tid < mrem ? tid : mrem - 1)];
    Pg = eg + ((size_t)z << 19);
    Pu = eu + ((size_t)z << 19);
    Cb = act_e + ((size_t)z * NT + rt * 128) * I_DIM;
    ldc = I_DIM;
  } else {
    mrem = 128;
    if (tid < 128) rows_s[tid] = rt * 128 + tid;
    Pg = sg;
    Pu = su;
    Cb = act_s + (size_t)rt * 128 * SI_DIM;
    ldc = SI_DIM;
  }
  __syncthreads();

  const int lane = tid & 63, wave = tid >> 6;
  const int mw = (wave >> 1) * 64, nw = (wave & 1) * 64;
  const int l15 = lane & 15, quad = lane >> 4;
  const int srow = tid >> 3;   // 0..31
  const int cch = tid & 7;     // chunk id (8 bf16 / 8 fp32 elems)
  const int p8 = cch * 8;
  const int sx = (l15 & 7) * 8;
  const int ctb = ct * 128;

  const bf16* ap[4];
  const float* bp[4];
  int alo[4], blo[4];
#pragma unroll
  for (int r = 0; r < 4; r++) {
    int R = srow + r * 32;
    ap[r] = xb + (size_t)rows_s[R] * H_DIM + ((cch ^ (R & 7)) * 8);
    alo[r] = R * 64 + p8;  // lane-ordered LDS dest (HW: base + lane*16)
    int idx = ctb + R;     // interleaved col index: blocks of 16 g,u,g,u...
    int b = idx >> 4;
    int sr = ((b >> 1) << 4) | (idx & 15);
    bp[r] = ((b & 1) ? Pu : Pg) + (size_t)sr * H_DIM + p8;
    blo[r] = R * 64 + ((cch ^ (R & 7)) * 8);  // swizzled ds_write slot
  }

  f32x4 acc[4][4] = {};
  for (int k0 = 0; k0 < H_DIM; k0 += 64) {
#pragma unroll
    for (int r = 0; r < 4; r++) glds16(ap[r] + k0, &As[alo[r]]);
#pragma unroll
    for (int r = 0; r < 4; r++) {
      f32x4 v0 = *(const f32x4*)(bp[r] + k0);
      f32x4 v1 = *(const f32x4*)(bp[r] + k0 + 4);
      *(bf16x8*)&Bs[blo[r]] = cvt8(v0, v1);
    }
    __syncthreads();
#pragma unroll
    for (int kk = 0; kk < 2; kk++) {
      const int ko = (kk * 4 + quad) * 8;
      bf16x8 av[4], bv[4];
#pragma unroll
      for (int i = 0; i < 4; i++) {
        av[i] = *(const bf16x8*)&As[(mw + i * 16 + l15) * 64 + (ko ^ sx)];
        bv[i] = *(const bf16x8*)&Bs[(nw + i * 16 + l15) * 64 + (ko ^ sx)];
      }
#pragma unroll
      for (int i = 0; i < 4; i++)
#pragma unroll
        for (int j = 0; j < 4; j++)
          acc[i][j] = __builtin_amdgcn_mfma_f32_16x16x32_bf16(av[i], bv[j], acc[i][j], 0, 0, 0);
    }
    __syncthreads();
  }

  // j even = gate, j odd = up (adjacent 16-col groups, same lane/reg)
#pragma unroll
  for (int i = 0; i < 4; i++) {
#pragma unroll
    for (int rg = 0; rg < 4; rg++) {
      int rl = mw + i * 16 + quad * 4 + rg;
      if (rl < mrem) {
#pragma unroll
        for (int jp = 0; jp < 2; jp++) {
          float g = acc[i][jp * 2][rg];
          float u = acc[i][jp * 2 + 1][rg];
          int c = ct * 64 + (nw >> 1) + jp * 16 + l15;
          Cb[(size_t)rl * ldc + c] = (bf16)((g / (1.f + __expf(-g))) * u);
        }
      }
    }
  }
}

// ---- down GEMM: A=act via glds16, B=fp32 down weights converted in-staging;
// epilogue atomicAdd(out, wm*y). grid (8,16,9).
__global__ __launch_bounds__(256, 2) void gemm_down(
    const float* __restrict__ ed, const float* __restrict__ sd,
    const bf16* __restrict__ act_e, const bf16* __restrict__ act_s,
    const int* __restrict__ cnt, const float* __restrict__ wm,
    const int* __restrict__ lists, float* __restrict__ out) {
  const int z = blockIdx.z, ct = blockIdx.x, rt = blockIdx.y;
  const int tid = threadIdx.x;
  __shared__ int rows_s[128];
  __shared__ __align__(16) bf16 As[128 * 64];
  __shared__ __align__(16) bf16 Bs[128 * 64];
  int K, mrem;
  const bf16* Ab;
  const float* Bbase;
  if (z < NE) {
    int c = cnt[z];
    if (rt * 128 >= c) return;
    mrem = c - rt * 128;
    if (tid < 128)
      rows_s[tid] = lists[z * NT + rt * 128 + (tid < mrem ? tid : mrem - 1)];
    Ab = act_e + ((size_t)z * NT + rt * 128) * I_DIM;
    K = I_DIM;
    Bbase = ed + (size_t)z * H_DIM * I_DIM;
  } else {
    mrem = 128;
    if (tid < 128) rows_s[tid] = rt * 128 + tid;
    Ab = act_s + (size_t)rt * 128 * SI_DIM;
    K = SI_DIM;
    Bbase = sd;
  }
  __syncthreads();

  const int lane = tid & 63, wave = tid >> 6;
  const int mw = (wave >> 1) * 64, nw = (wave & 1) * 64;
  const int l15 = lane & 15, quad = lane >> 4;
  const int srow = tid >> 3;
  const int cch = tid & 7;
  const int p8 = cch * 8;
  const int sx = (l15 & 7) * 8;

  const bf16* ap[4];
  const float* bp[4];
  int alo[4], blo[4];
#pragma unroll
  for (int r = 0; r < 4; r++) {
    int R = srow + r * 32;
    ap[r] = Ab + (size_t)R * K + ((cch ^ (R & 7)) * 8);
    alo[r] = R * 64 + p8;
    bp[r] = Bbase + (size_t)(ct * 128 + R) * K + p8;
    blo[r] = R * 64 + ((cch ^ (R & 7)) * 8);
  }

  f32x4 acc[4][4] = {};
  for (int k0 = 0; k0 < K; k0 += 64) {
#pragma unroll
    for (int r = 0; r < 4; r++) glds16(ap[r] + k0, &As[alo[r]]);
#pragma unroll
    for (int r = 0; r < 4; r++) {
      f32x4 v0 = *(const f32x4*)(bp[r] + k0);
      f32x4 v1 = *(const f32x4*)(bp[r] + k0 + 4);
      *(bf16x8*)&Bs[blo[r]] = cvt8(v0, v1);
    }
    __syncthreads();
#pragma unroll
    for (int kk = 0; kk < 2; kk++) {
      const int ko = (kk * 4 + quad) * 8;
      bf16x8 av[4], bv[4];
#pragma unroll
      for (int i = 0; i < 4; i++) {
        av[i] = *(const bf16x8*)&As[(mw + i * 16 + l15) * 64 + (ko ^ sx)];
        bv[i] = *(const bf16x8*)&Bs[(nw + i * 16 + l15) * 64 + (ko ^ sx)];
      }
#pragma unroll
      for (int i = 0; i < 4; i++)
#pragma unroll
        for (int j = 0; j < 4; j++)
          acc[i][j] = __builtin_amdgcn_mfma_f32_16x16x32_bf16(av[i], bv[j], acc[i][j], 0, 0, 0);
    }
    __syncthreads();
  }

  const float wsc = (z < NE) ? wm[z] : 1.f;
#pragma unroll
  for (int i = 0; i < 4; i++) {
#pragma unroll
    for (int rg = 0; rg < 4; rg++) {
      int rl = mw + i * 16 + quad * 4 + rg;
      if (rl < mrem) {
        int t = rows_s[rl];
        float* orow = out + (size_t)t * H_DIM + ct * 128 + nw;
#pragma unroll
        for (int j = 0; j < 4; j++)
          atomicAdd(&orow[j * 16 + l15], wsc * acc[i][j][rg]);
      }
    }
  }
}

extern "C" void kernel_launch(void* const* d_in, const int* in_sizes, int n_in,
                              void* d_out, int out_size, void* d_ws,
                              size_t ws_size, hipStream_t stream) {
  (void)in_sizes; (void)n_in; (void)out_size; (void)ws_size;
  const float* x  = (const float*)d_in[0];
  const float* gw = (const float*)d_in[1];
  const float* lb = (const float*)d_in[2];
  const float* eg = (const float*)d_in[3];
  const float* eu = (const float*)d_in[4];
  const float* ed = (const float*)d_in[5];
  const float* sg = (const float*)d_in[6];
  const float* su = (const float*)d_in[7];
  const float* sd = (const float*)d_in[8];
  float* out = (float*)d_out;
  char* ws = (char*)d_ws;

  int* cnt     = (int*)(ws + OFF_CNT);
  float* wm    = (float*)(ws + OFF_WM);
  int2* topi   = (int2*)(ws + OFF_TOPI);
  float2* topw = (float2*)(ws + OFF_TOPW);
  int* lists   = (int*)(ws + OFF_LISTS);
  bf16* xb     = (bf16*)(ws + OFF_XB);
  bf16* act_e  = (bf16*)(ws + OFF_ACTE);
  bf16* act_s  = (bf16*)(ws + OFF_ACTS);

  hipMemsetAsync(d_out, 0, (size_t)NT * H_DIM * sizeof(float), stream);
  router_kernel<<<NT / 4, 256, 0, stream>>>(x, gw, lb, xb, topi, topw);
  build_kernel<<<NE, 256, 0, stream>>>(topi, topw, cnt, wm, lists);
  gemm_gu<<<dim3(16, 16, 9), 256, 0, stream>>>(eg, eu, sg, su, xb, cnt, lists,
                                               act_e, act_s);
  gemm_down<<<dim3(8, 16, 9), 256, 0, stream>>>(ed, sd, act_e, act_s, cnt, wm,
                                                lists, out);
}